// Round 1
// baseline (1115.497 us; speedup 1.0000x reference)
//
#include <hip/hip_runtime.h>
#include <hip/hip_bf16.h>
#include <cstdint>
#include <cstddef>

typedef unsigned short u16;
typedef __bf16 bf16x8 __attribute__((ext_vector_type(8)));
typedef float f32x4 __attribute__((ext_vector_type(4)));

__device__ __forceinline__ float b2f(u16 u) {
  return __builtin_bit_cast(float, (unsigned)u << 16);
}
__device__ __forceinline__ u16 f2b(float f) {
  unsigned u = __builtin_bit_cast(unsigned, f);
  u += 0x7FFFu + ((u >> 16) & 1u);   // round-to-nearest-even
  return (u16)(u >> 16);
}

// ---------------- f32 -> bf16 convert (4 elems/thread) ----------------
__global__ __launch_bounds__(256) void cvt_kernel(const float* __restrict__ src,
                                                  u16* __restrict__ dst, int n4) {
  int i = blockIdx.x * 256 + threadIdx.x;
  if (i < n4) {
    float4 f = ((const float4*)src)[i];
    ushort4 o;
    o.x = f2b(f.x); o.y = f2b(f.y); o.z = f2b(f.z); o.w = f2b(f.w);
    ((ushort4*)dst)[i] = o;
  }
}

// ---------------- GEMM: C(bf16, MxN) = A(bf16, MxK) @ W(bf16, NxK)^T + bias [+bias2] [gelu] ----
// 128x128 tile, BK=32, 256 threads = 4 waves, each wave 64x64 via 4x4 mfma 16x16x32.
template<int EPI>  // 0 = none, 1 = exact gelu
__global__ __launch_bounds__(256)
void gemm_bt(const u16* __restrict__ A, const u16* __restrict__ W,
             const float* __restrict__ bias, const float* __restrict__ bias2,
             u16* __restrict__ C, int N, int K)
{
  __shared__ alignas(16) u16 As[128][32];
  __shared__ alignas(16) u16 Bs[128][32];
  const int tid  = threadIdx.x;
  const int lane = tid & 63;
  const int wave = tid >> 6;
  const int nTiles = N >> 7;
  const int bm = blockIdx.x / nTiles;
  const int bn = blockIdx.x % nTiles;
  const size_t row0 = (size_t)bm << 7;
  const int col0 = bn << 7;

  // staging: thread t loads rows (t>>2) and (t>>2)+64, 8 bf16 at col (t&3)*8
  const int sRow = tid >> 2;
  const int sCol = (tid & 3) << 3;
  const u16* Ap0 = A + (row0 + sRow) * K + sCol;
  const u16* Ap1 = A + (row0 + sRow + 64) * K + sCol;
  const u16* Wp0 = W + (size_t)(col0 + sRow) * K + sCol;
  const u16* Wp1 = W + (size_t)(col0 + sRow + 64) * K + sCol;

  const int wm = (wave >> 1) << 6;   // wave row offset in tile
  const int wn = (wave & 1) << 6;    // wave col offset in tile
  const int fr = lane & 15;          // fragment row (A) / col (B)
  const int kb = (lane >> 4) << 3;   // k base within 32

  f32x4 acc[4][4];
  {
    f32x4 z = {0.f, 0.f, 0.f, 0.f};
#pragma unroll
    for (int m = 0; m < 4; ++m)
#pragma unroll
      for (int n = 0; n < 4; ++n) acc[m][n] = z;
  }

  for (int k0 = 0; k0 < K; k0 += 32) {
    __syncthreads();   // protect previous iteration's LDS reads
    *(int4*)(&As[sRow][sCol])      = *(const int4*)(Ap0 + k0);
    *(int4*)(&As[sRow + 64][sCol]) = *(const int4*)(Ap1 + k0);
    *(int4*)(&Bs[sRow][sCol])      = *(const int4*)(Wp0 + k0);
    *(int4*)(&Bs[sRow + 64][sCol]) = *(const int4*)(Wp1 + k0);
    __syncthreads();
    bf16x8 af[4], bfr[4];
#pragma unroll
    for (int m = 0; m < 4; ++m) af[m]  = *(const bf16x8*)(&As[wm + m*16 + fr][kb]);
#pragma unroll
    for (int n = 0; n < 4; ++n) bfr[n] = *(const bf16x8*)(&Bs[wn + n*16 + fr][kb]);
#pragma unroll
    for (int m = 0; m < 4; ++m)
#pragma unroll
      for (int n = 0; n < 4; ++n)
        acc[m][n] = __builtin_amdgcn_mfma_f32_16x16x32_bf16(af[m], bfr[n], acc[m][n], 0, 0, 0);
  }

  // epilogue: C/D layout col=lane&15, row=(lane>>4)*4+r
  const int orow = (lane >> 4) << 2;
#pragma unroll
  for (int n = 0; n < 4; ++n) {
    const int gcol = col0 + wn + n*16 + fr;
    float bb = 0.f;
    if (bias)  bb += bias[gcol];
    if (bias2) bb += bias2[gcol];
#pragma unroll
    for (int m = 0; m < 4; ++m) {
#pragma unroll
      for (int r = 0; r < 4; ++r) {
        const size_t grow = row0 + wm + m*16 + orow + r;
        float v = acc[m][n][r] + bb;
        if (EPI == 1) v = 0.5f * v * (1.f + erff(v * 0.70710678118654752f));
        C[grow * N + gcol] = f2b(v);
      }
    }
  }
}

// ---------------- LayerNorm of residual sum: O = LN(X + Y) * g + b, row width 1024 ----
__global__ __launch_bounds__(256)
void ln_res(const u16* __restrict__ X, const u16* __restrict__ Y,
            const float* __restrict__ g, const float* __restrict__ bta,
            u16* __restrict__ O)
{
  const int row = blockIdx.x;
  const int tid = threadIdx.x;
  const size_t base = (size_t)row * 1024 + tid * 4;
  ushort4 xv = *(const ushort4*)(X + base);
  ushort4 yv = *(const ushort4*)(Y + base);
  float v0 = b2f(xv.x) + b2f(yv.x);
  float v1 = b2f(xv.y) + b2f(yv.y);
  float v2 = b2f(xv.z) + b2f(yv.z);
  float v3 = b2f(xv.w) + b2f(yv.w);
  float s  = v0 + v1 + v2 + v3;
  float ss = v0*v0 + v1*v1 + v2*v2 + v3*v3;
#pragma unroll
  for (int off = 32; off; off >>= 1) {
    s  += __shfl_down(s, off);
    ss += __shfl_down(ss, off);
  }
  __shared__ float red[8];
  if ((tid & 63) == 0) { red[tid >> 6] = s; red[4 + (tid >> 6)] = ss; }
  __syncthreads();
  const float S  = red[0] + red[1] + red[2] + red[3];
  const float SS = red[4] + red[5] + red[6] + red[7];
  const float mu  = S * (1.f / 1024.f);
  const float inv = rsqrtf(SS * (1.f / 1024.f) - mu * mu + 1e-5f);
  const int n = tid * 4;
  float4 gv = *(const float4*)(g + n);
  float4 bv = *(const float4*)(bta + n);
  ushort4 o;
  o.x = f2b((v0 - mu) * inv * gv.x + bv.x);
  o.y = f2b((v1 - mu) * inv * gv.y + bv.y);
  o.z = f2b((v2 - mu) * inv * gv.z + bv.z);
  o.w = f2b((v3 - mu) * inv * gv.w + bv.w);
  *(ushort4*)(O + base) = o;
}

// ---------------- 2-key attention combine, 8 heads of d=128 ----------------
// O[row] per head h: softmax([q0.k0, q0.k1]/sqrt(128)) @ [v0; v1]
__global__ __launch_bounds__(256)
void attn2(const u16* __restrict__ Q, const u16* __restrict__ K0, const u16* __restrict__ K1,
           const u16* __restrict__ V0, const u16* __restrict__ V1, u16* __restrict__ O)
{
  const int row = blockIdx.x;
  const int tid = threadIdx.x;
  const size_t base = (size_t)row * 1024 + tid * 4;
  ushort4 qv  = *(const ushort4*)(Q  + base);
  ushort4 k0v = *(const ushort4*)(K0 + base);
  ushort4 k1v = *(const ushort4*)(K1 + base);
  ushort4 v0v = *(const ushort4*)(V0 + base);
  ushort4 v1v = *(const ushort4*)(V1 + base);
  float q0 = b2f(qv.x), q1 = b2f(qv.y), q2 = b2f(qv.z), q3 = b2f(qv.w);
  float d0 = q0*b2f(k0v.x) + q1*b2f(k0v.y) + q2*b2f(k0v.z) + q3*b2f(k0v.w);
  float d1 = q0*b2f(k1v.x) + q1*b2f(k1v.y) + q2*b2f(k1v.z) + q3*b2f(k1v.w);
  // head = tid>>5 (32 threads * 4 elems = 128 = head dim); reduce within 32-lane group
#pragma unroll
  for (int off = 16; off; off >>= 1) {
    d0 += __shfl_xor(d0, off);
    d1 += __shfl_xor(d1, off);
  }
  const float sc = 0.088388347648318447f;  // 1/sqrt(128)
  float s0 = d0 * sc, s1 = d1 * sc;
  float mx = fmaxf(s0, s1);
  float e0 = expf(s0 - mx), e1 = expf(s1 - mx);
  float r = 1.f / (e0 + e1);
  float a0 = e0 * r, a1 = e1 * r;
  ushort4 o;
  o.x = f2b(a0 * b2f(v0v.x) + a1 * b2f(v1v.x));
  o.y = f2b(a0 * b2f(v0v.y) + a1 * b2f(v1v.y));
  o.z = f2b(a0 * b2f(v0v.z) + a1 * b2f(v1v.z));
  o.w = f2b(a0 * b2f(v0v.w) + a1 * b2f(v1v.w));
  *(ushort4*)(O + base) = o;
}

// ---------------- final: out[row] = dot(LN(X + Y)*g + b, Wc) + bc ----------------
__global__ __launch_bounds__(256)
void final_k(const u16* __restrict__ X, const u16* __restrict__ Y,
             const float* __restrict__ g, const float* __restrict__ bta,
             const float* __restrict__ Wc, const float* __restrict__ bc,
             float* __restrict__ out)
{
  const int row = blockIdx.x;
  const int tid = threadIdx.x;
  const size_t base = (size_t)row * 1024 + tid * 4;
  ushort4 xv = *(const ushort4*)(X + base);
  ushort4 yv = *(const ushort4*)(Y + base);
  float v0 = b2f(xv.x) + b2f(yv.x);
  float v1 = b2f(xv.y) + b2f(yv.y);
  float v2 = b2f(xv.z) + b2f(yv.z);
  float v3 = b2f(xv.w) + b2f(yv.w);
  float s  = v0 + v1 + v2 + v3;
  float ss = v0*v0 + v1*v1 + v2*v2 + v3*v3;
#pragma unroll
  for (int off = 32; off; off >>= 1) {
    s  += __shfl_down(s, off);
    ss += __shfl_down(ss, off);
  }
  __shared__ float red[8];
  __shared__ float red2[4];
  if ((tid & 63) == 0) { red[tid >> 6] = s; red[4 + (tid >> 6)] = ss; }
  __syncthreads();
  const float S  = red[0] + red[1] + red[2] + red[3];
  const float SS = red[4] + red[5] + red[6] + red[7];
  const float mu  = S * (1.f / 1024.f);
  const float inv = rsqrtf(SS * (1.f / 1024.f) - mu * mu + 1e-5f);
  const int n = tid * 4;
  float4 gv = *(const float4*)(g + n);
  float4 bv = *(const float4*)(bta + n);
  float4 wv = *(const float4*)(Wc + n);
  float dot = ((v0 - mu) * inv * gv.x + bv.x) * wv.x
            + ((v1 - mu) * inv * gv.y + bv.y) * wv.y
            + ((v2 - mu) * inv * gv.z + bv.z) * wv.z
            + ((v3 - mu) * inv * gv.w + bv.w) * wv.w;
#pragma unroll
  for (int off = 32; off; off >>= 1) dot += __shfl_down(dot, off);
  if ((tid & 63) == 0) red2[tid >> 6] = dot;
  __syncthreads();
  if (tid == 0) out[row] = red2[0] + red2[1] + red2[2] + red2[3] + bc[0];
}

// =====================================================================
extern "C" void kernel_launch(void* const* d_in, const int* in_sizes, int n_in,
                              void* d_out, int out_size, void* d_ws, size_t ws_size,
                              hipStream_t stream) {
  const float* spatial = (const float*)d_in[0];
  const float* freq    = (const float*)d_in[1];
  const float* Wps   = (const float*)d_in[2];
  const float* bps   = (const float*)d_in[3];
  const float* Wpf   = (const float*)d_in[4];
  const float* bpf   = (const float*)d_in[5];
  const float* pos_s = (const float*)d_in[6];
  const float* pos_f = (const float*)d_in[7];
  // d_in[8], d_in[9], d_in[11], d_in[12] (ca_Wq/ca_Wk/ca_bq/ca_bk) are dead: softmax over 1 key == 1
  const float* ca_Wv = (const float*)d_in[10];
  const float* ca_bv = (const float*)d_in[13];
  const float* ca_Wo = (const float*)d_in[14];
  const float* ca_bo = (const float*)d_in[15];
  const float* n1_g  = (const float*)d_in[16];
  const float* n1_b  = (const float*)d_in[17];
  const float* W1    = (const float*)d_in[18];
  const float* b1    = (const float*)d_in[19];
  const float* W2    = (const float*)d_in[20];
  const float* b2    = (const float*)d_in[21];
  const float* n2_g  = (const float*)d_in[22];
  const float* n2_b  = (const float*)d_in[23];
  const float* sWq   = (const float*)d_in[24];
  const float* sWk   = (const float*)d_in[25];
  const float* sWv   = (const float*)d_in[26];
  const float* sbq   = (const float*)d_in[27];
  const float* sbk   = (const float*)d_in[28];
  const float* sbv   = (const float*)d_in[29];
  const float* sWo   = (const float*)d_in[30];
  const float* sbo   = (const float*)d_in[31];
  const float* n3_g  = (const float*)d_in[32];
  const float* n3_b  = (const float*)d_in[33];
  const float* Wc    = (const float*)d_in[34];
  const float* bc    = (const float*)d_in[35];

  const int Bn = 16384;
  constexpr size_t SZ_BIG = (size_t)16384 * 2048 * 2;   // 67,108,864
  constexpr size_t SZ_ACT = (size_t)16384 * 1024 * 2;   // 33,554,432
  constexpr size_t OFF_S = 0;
  constexpr size_t OFF_A = OFF_S + SZ_BIG;
  constexpr size_t OFF_B = OFF_A + SZ_ACT;
  constexpr size_t OFF_C = OFF_B + SZ_ACT;
  constexpr size_t OFF_D = OFF_C + SZ_ACT;
  constexpr size_t OFF_E = OFF_D + SZ_ACT;
  constexpr size_t OFF_F = OFF_E + SZ_ACT;
  constexpr size_t OFF_W = OFF_F + SZ_ACT;

  uint8_t* ws = (uint8_t*)d_ws;
  u16* S_b  = (u16*)(ws + OFF_S);             // spatial bf16 (later Gb; later q0|k0)
  u16* F_b  = (u16*)(ws + OFF_A);             // freq bf16    (later v0)
  u16* Qb   = (u16*)(ws + OFF_B);             // (later Hb; later k1)
  u16* KVb  = (u16*)(ws + OFF_C);             // (later Ob)
  u16* Vb   = (u16*)(ws + OFF_D);             // (later X2b)
  u16* AOb  = (u16*)(ws + OFF_E);             // (later v1)
  u16* X1b  = (u16*)(ws + OFF_F);             // (later POb)

  u16* wWps = (u16*)(ws + OFF_W);
  u16* wWpf = wWps + (size_t)1024 * 2048;
  u16* wWv  = wWpf + (size_t)1024 * 1024;
  u16* wWo  = wWv  + (size_t)1024 * 1024;
  u16* wW1  = wWo  + (size_t)1024 * 1024;
  u16* wW2  = wW1  + (size_t)2048 * 1024;
  u16* wSq  = wW2  + (size_t)1024 * 2048;
  u16* wSk  = wSq  + (size_t)1024 * 1024;
  u16* wSv  = wSk  + (size_t)1024 * 1024;
  u16* wSo  = wSv  + (size_t)1024 * 1024;

  // aliases (phase-based reuse)
  u16* Gb  = (u16*)(ws + OFF_S);
  u16* Hb  = (u16*)(ws + OFF_B);
  u16* X2b = (u16*)(ws + OFF_D);
  u16* q0  = (u16*)(ws + OFF_S);
  u16* k0  = (u16*)(ws + OFF_S + SZ_ACT);
  u16* v0  = (u16*)(ws + OFF_A);
  u16* k1  = (u16*)(ws + OFF_B);
  u16* v1  = (u16*)(ws + OFF_E);
  u16* Ob  = (u16*)(ws + OFF_C);
  u16* POb = (u16*)(ws + OFF_F);

  auto cvt = [&](const float* src, u16* dst, size_t n) {
    int n4 = (int)(n >> 2);
    cvt_kernel<<<dim3((n4 + 255) / 256), dim3(256), 0, stream>>>(src, dst, n4);
  };
  auto gemm = [&](const u16* A_, const u16* W_, const float* bias, const float* bias2,
                  u16* C_, int N, int K, bool gelu) {
    dim3 grid(128 * (N >> 7));
    if (gelu) gemm_bt<1><<<grid, dim3(256), 0, stream>>>(A_, W_, bias, bias2, C_, N, K);
    else      gemm_bt<0><<<grid, dim3(256), 0, stream>>>(A_, W_, bias, bias2, C_, N, K);
  };

  // 0) convert inputs + weights to bf16
  cvt(spatial, S_b, (size_t)Bn * 2048);
  cvt(freq,    F_b, (size_t)Bn * 1024);
  cvt(Wps, wWps, (size_t)1024 * 2048);
  cvt(Wpf, wWpf, (size_t)1024 * 1024);
  cvt(ca_Wv, wWv, (size_t)1024 * 1024);
  cvt(ca_Wo, wWo, (size_t)1024 * 1024);
  cvt(W1, wW1, (size_t)2048 * 1024);
  cvt(W2, wW2, (size_t)1024 * 2048);
  cvt(sWq, wSq, (size_t)1024 * 1024);
  cvt(sWk, wSk, (size_t)1024 * 1024);
  cvt(sWv, wSv, (size_t)1024 * 1024);
  cvt(sWo, wSo, (size_t)1024 * 1024);

  // 1) Q = spatial @ Wps^T + bps + pos_s
  gemm(S_b, wWps, bps, pos_s, Qb, 1024, 2048, false);
  // 2) KV = freq @ Wpf^T + bpf + pos_f
  gemm(F_b, wWpf, bpf, pos_f, KVb, 1024, 1024, false);
  // 3) V = KV @ ca_Wv^T + ca_bv ; 4) AO = V @ ca_Wo^T + ca_bo  (cross-attn collapsed)
  gemm(KVb, wWv, ca_bv, nullptr, Vb, 1024, 1024, false);
  gemm(Vb, wWo, ca_bo, nullptr, AOb, 1024, 1024, false);
  // 5) X1 = LN(Q + AO)
  ln_res<<<dim3(Bn), dim3(256), 0, stream>>>(Qb, AOb, n1_g, n1_b, X1b);
  // 6) G = gelu(X1 @ W1^T + b1) ; 7) H = G @ W2^T + b2
  gemm(X1b, wW1, b1, nullptr, Gb, 2048, 1024, true);
  gemm(Gb, wW2, b2, nullptr, Hb, 1024, 2048, false);
  // 8) X2 = LN(X1 + H)
  ln_res<<<dim3(Bn), dim3(256), 0, stream>>>(X1b, Hb, n2_g, n2_b, X2b);
  // 9-13) self-attn projections (only what token-0 output needs)
  gemm(X2b, wSq, sbq, nullptr, q0, 1024, 1024, false);
  gemm(X2b, wSk, sbk, nullptr, k0, 1024, 1024, false);
  gemm(X2b, wSv, sbv, nullptr, v0, 1024, 1024, false);
  gemm(KVb, wSk, sbk, nullptr, k1, 1024, 1024, false);
  gemm(KVb, wSv, sbv, nullptr, v1, 1024, 1024, false);
  // 14) 2-key attention combine per head
  attn2<<<dim3(Bn), dim3(256), 0, stream>>>(q0, k0, k1, v0, v1, Ob);
  // 15) PO = O @ sa_Wo^T + sa_bo
  gemm(Ob, wSo, sbo, nullptr, POb, 1024, 1024, false);
  // 16) out = LN(X2 + PO; n3) . Wc + bc
  final_k<<<dim3(Bn), dim3(256), 0, stream>>>(X2b, POb, n3_g, n3_b, Wc, bc, (float*)d_out);
}

// Round 2
// 1035.986 us; speedup vs baseline: 1.0767x; 1.0767x over previous
//
#include <hip/hip_runtime.h>
#include <hip/hip_bf16.h>
#include <cstdint>
#include <cstddef>

typedef unsigned short u16;
typedef __bf16 bf16x8 __attribute__((ext_vector_type(8)));
typedef float f32x4 __attribute__((ext_vector_type(4)));

#define GLOBAL_AS(p) ((const __attribute__((address_space(1))) void*)(p))
#define LDS_AS(p)    ((__attribute__((address_space(3))) void*)(p))

__device__ __forceinline__ float b2f(u16 u) {
  return __builtin_bit_cast(float, (unsigned)u << 16);
}
__device__ __forceinline__ u16 f2b(float f) {
  unsigned u = __builtin_bit_cast(unsigned, f);
  u += 0x7FFFu + ((u >> 16) & 1u);   // round-to-nearest-even
  return (u16)(u >> 16);
}

// ---------------- f32 -> bf16 convert (4 elems/thread) ----------------
__global__ __launch_bounds__(256) void cvt_kernel(const float* __restrict__ src,
                                                  u16* __restrict__ dst, int n4) {
  int i = blockIdx.x * 256 + threadIdx.x;
  if (i < n4) {
    float4 f = ((const float4*)src)[i];
    ushort4 o;
    o.x = f2b(f.x); o.y = f2b(f.y); o.z = f2b(f.z); o.w = f2b(f.w);
    ((ushort4*)dst)[i] = o;
  }
}

// ---------------- GEMM: C(bf16, MxN) = A(bf16, MxK) @ W(bf16, NxK)^T + bias [+bias2] [gelu] ----
// 128x128 tile, BK=32, 256 threads = 4 waves, each wave 64x64 via 4x4 mfma 16x16x32.
// Staging via global_load_lds width=16 (m97 structure).
template<int EPI>  // 0 = none, 1 = exact gelu
__global__ __launch_bounds__(256)
void gemm_bt(const u16* __restrict__ A, const u16* __restrict__ W,
             const float* __restrict__ bias, const float* __restrict__ bias2,
             u16* __restrict__ C, int N, int K)
{
  __shared__ alignas(16) u16 As[128][32];
  __shared__ alignas(16) u16 Bs[128][32];
  const int tid  = threadIdx.x;
  const int lane = tid & 63;
  const int wave = tid >> 6;
  const int nTiles = N >> 7;
  const int bm = blockIdx.x / nTiles;
  const int bn = blockIdx.x % nTiles;
  const size_t row0 = (size_t)bm << 7;
  const int col0 = bn << 7;

  // async staging: per wave-call, 16 rows x 32 cols (1 KiB). lane l -> row l>>2, col (l&3)*8.
  // LDS dest is wave-uniform base + lane*16B (hardware rule), matching linear As/Bs rows.
  const int srow = lane >> 2;
  const int scol = (lane & 3) << 3;
  const int ra = wave << 4;                     // wave row base: 0,16,32,48
  const u16* gA0 = A + (row0 + ra + srow) * K + scol;
  const u16* gA1 = gA0 + (size_t)64 * K;
  const u16* gB0 = W + ((size_t)col0 + ra + srow) * K + scol;
  const u16* gB1 = gB0 + (size_t)64 * K;
  u16* lA0 = &As[ra][0];
  u16* lA1 = &As[64 + ra][0];
  u16* lB0 = &Bs[ra][0];
  u16* lB1 = &Bs[64 + ra][0];

  const int wm = (wave >> 1) << 6;   // wave row offset in tile
  const int wn = (wave & 1) << 6;    // wave col offset in tile
  const int fr = lane & 15;          // fragment row (A) / col (B)
  const int kb = (lane >> 4) << 3;   // k base within 32

  f32x4 acc[4][4];
  {
    f32x4 z = {0.f, 0.f, 0.f, 0.f};
#pragma unroll
    for (int m = 0; m < 4; ++m)
#pragma unroll
      for (int n = 0; n < 4; ++n) acc[m][n] = z;
  }

  for (int k0 = 0; k0 < K; k0 += 32) {
    __syncthreads();   // previous iteration's LDS reads complete
    __builtin_amdgcn_global_load_lds(GLOBAL_AS(gA0 + k0), LDS_AS(lA0), 16, 0, 0);
    __builtin_amdgcn_global_load_lds(GLOBAL_AS(gA1 + k0), LDS_AS(lA1), 16, 0, 0);
    __builtin_amdgcn_global_load_lds(GLOBAL_AS(gB0 + k0), LDS_AS(lB0), 16, 0, 0);
    __builtin_amdgcn_global_load_lds(GLOBAL_AS(gB1 + k0), LDS_AS(lB1), 16, 0, 0);
    __syncthreads();   // implies s_waitcnt vmcnt(0) drain of the LDS-DMA
    bf16x8 af[4], bfr[4];
#pragma unroll
    for (int m = 0; m < 4; ++m) af[m]  = *(const bf16x8*)(&As[wm + m*16 + fr][kb]);
#pragma unroll
    for (int n = 0; n < 4; ++n) bfr[n] = *(const bf16x8*)(&Bs[wn + n*16 + fr][kb]);
#pragma unroll
    for (int m = 0; m < 4; ++m)
#pragma unroll
      for (int n = 0; n < 4; ++n)
        acc[m][n] = __builtin_amdgcn_mfma_f32_16x16x32_bf16(af[m], bfr[n], acc[m][n], 0, 0, 0);
  }

  // epilogue: C/D layout col=lane&15, row=(lane>>4)*4+r
  const int orow = (lane >> 4) << 2;
#pragma unroll
  for (int n = 0; n < 4; ++n) {
    const int gcol = col0 + wn + n*16 + fr;
    float bb = 0.f;
    if (bias)  bb += bias[gcol];
    if (bias2) bb += bias2[gcol];
#pragma unroll
    for (int m = 0; m < 4; ++m) {
#pragma unroll
      for (int r = 0; r < 4; ++r) {
        const size_t grow = row0 + wm + m*16 + orow + r;
        float v = acc[m][n][r] + bb;
        if (EPI == 1) v = 0.5f * v * (1.f + erff(v * 0.70710678118654752f));
        C[grow * N + gcol] = f2b(v);
      }
    }
  }
}

// ---------------- LayerNorm of residual sum: O = LN(X + Y) * g + b, row width 1024 ----
__global__ __launch_bounds__(256)
void ln_res(const u16* __restrict__ X, const u16* __restrict__ Y,
            const float* __restrict__ g, const float* __restrict__ bta,
            u16* __restrict__ O)
{
  const int row = blockIdx.x;
  const int tid = threadIdx.x;
  const size_t base = (size_t)row * 1024 + tid * 4;
  ushort4 xv = *(const ushort4*)(X + base);
  ushort4 yv = *(const ushort4*)(Y + base);
  float v0 = b2f(xv.x) + b2f(yv.x);
  float v1 = b2f(xv.y) + b2f(yv.y);
  float v2 = b2f(xv.z) + b2f(yv.z);
  float v3 = b2f(xv.w) + b2f(yv.w);
  float s  = v0 + v1 + v2 + v3;
  float ss = v0*v0 + v1*v1 + v2*v2 + v3*v3;
#pragma unroll
  for (int off = 32; off; off >>= 1) {
    s  += __shfl_down(s, off);
    ss += __shfl_down(ss, off);
  }
  __shared__ float red[8];
  if ((tid & 63) == 0) { red[tid >> 6] = s; red[4 + (tid >> 6)] = ss; }
  __syncthreads();
  const float S  = red[0] + red[1] + red[2] + red[3];
  const float SS = red[4] + red[5] + red[6] + red[7];
  const float mu  = S * (1.f / 1024.f);
  const float inv = rsqrtf(SS * (1.f / 1024.f) - mu * mu + 1e-5f);
  const int n = tid * 4;
  float4 gv = *(const float4*)(g + n);
  float4 bv = *(const float4*)(bta + n);
  ushort4 o;
  o.x = f2b((v0 - mu) * inv * gv.x + bv.x);
  o.y = f2b((v1 - mu) * inv * gv.y + bv.y);
  o.z = f2b((v2 - mu) * inv * gv.z + bv.z);
  o.w = f2b((v3 - mu) * inv * gv.w + bv.w);
  *(ushort4*)(O + base) = o;
}

// ---------------- 2-key attention combine, 8 heads of d=128 (strided inputs) ----------------
__global__ __launch_bounds__(256)
void attn2(const u16* __restrict__ Q, const u16* __restrict__ K0, const u16* __restrict__ V0, int sQ,
           const u16* __restrict__ K1, const u16* __restrict__ V1, int sK,
           u16* __restrict__ O)
{
  const int row = blockIdx.x;
  const int tid = threadIdx.x;
  const size_t bq = (size_t)row * sQ + tid * 4;
  const size_t bk = (size_t)row * sK + tid * 4;
  const size_t bo = (size_t)row * 1024 + tid * 4;
  ushort4 qv  = *(const ushort4*)(Q  + bq);
  ushort4 k0v = *(const ushort4*)(K0 + bq);
  ushort4 v0v = *(const ushort4*)(V0 + bq);
  ushort4 k1v = *(const ushort4*)(K1 + bk);
  ushort4 v1v = *(const ushort4*)(V1 + bk);
  float q0 = b2f(qv.x), q1 = b2f(qv.y), q2 = b2f(qv.z), q3 = b2f(qv.w);
  float d0 = q0*b2f(k0v.x) + q1*b2f(k0v.y) + q2*b2f(k0v.z) + q3*b2f(k0v.w);
  float d1 = q0*b2f(k1v.x) + q1*b2f(k1v.y) + q2*b2f(k1v.z) + q3*b2f(k1v.w);
  // head = tid>>5 (32 threads * 4 elems = 128 = head dim); reduce within 32-lane group
#pragma unroll
  for (int off = 16; off; off >>= 1) {
    d0 += __shfl_xor(d0, off);
    d1 += __shfl_xor(d1, off);
  }
  const float sc = 0.088388347648318447f;  // 1/sqrt(128)
  float s0 = d0 * sc, s1 = d1 * sc;
  float mx = fmaxf(s0, s1);
  float e0 = expf(s0 - mx), e1 = expf(s1 - mx);
  float r = 1.f / (e0 + e1);
  float a0 = e0 * r, a1 = e1 * r;
  ushort4 o;
  o.x = f2b(a0 * b2f(v0v.x) + a1 * b2f(v1v.x));
  o.y = f2b(a0 * b2f(v0v.y) + a1 * b2f(v1v.y));
  o.z = f2b(a0 * b2f(v0v.z) + a1 * b2f(v1v.z));
  o.w = f2b(a0 * b2f(v0v.w) + a1 * b2f(v1v.w));
  *(ushort4*)(O + bo) = o;
}

// ---------------- final: out[row] = dot(LN(X + Y)*g + b, Wc) + bc ----------------
__global__ __launch_bounds__(256)
void final_k(const u16* __restrict__ X, const u16* __restrict__ Y,
             const float* __restrict__ g, const float* __restrict__ bta,
             const float* __restrict__ Wc, const float* __restrict__ bc,
             float* __restrict__ out)
{
  const int row = blockIdx.x;
  const int tid = threadIdx.x;
  const size_t base = (size_t)row * 1024 + tid * 4;
  ushort4 xv = *(const ushort4*)(X + base);
  ushort4 yv = *(const ushort4*)(Y + base);
  float v0 = b2f(xv.x) + b2f(yv.x);
  float v1 = b2f(xv.y) + b2f(yv.y);
  float v2 = b2f(xv.z) + b2f(yv.z);
  float v3 = b2f(xv.w) + b2f(yv.w);
  float s  = v0 + v1 + v2 + v3;
  float ss = v0*v0 + v1*v1 + v2*v2 + v3*v3;
#pragma unroll
  for (int off = 32; off; off >>= 1) {
    s  += __shfl_down(s, off);
    ss += __shfl_down(ss, off);
  }
  __shared__ float red[8];
  __shared__ float red2[4];
  if ((tid & 63) == 0) { red[tid >> 6] = s; red[4 + (tid >> 6)] = ss; }
  __syncthreads();
  const float S  = red[0] + red[1] + red[2] + red[3];
  const float SS = red[4] + red[5] + red[6] + red[7];
  const float mu  = S * (1.f / 1024.f);
  const float inv = rsqrtf(SS * (1.f / 1024.f) - mu * mu + 1e-5f);
  const int n = tid * 4;
  float4 gv = *(const float4*)(g + n);
  float4 bv = *(const float4*)(bta + n);
  float4 wv = *(const float4*)(Wc + n);
  float dot = ((v0 - mu) * inv * gv.x + bv.x) * wv.x
            + ((v1 - mu) * inv * gv.y + bv.y) * wv.y
            + ((v2 - mu) * inv * gv.z + bv.z) * wv.z
            + ((v3 - mu) * inv * gv.w + bv.w) * wv.w;
#pragma unroll
  for (int off = 32; off; off >>= 1) dot += __shfl_down(dot, off);
  if ((tid & 63) == 0) red2[tid >> 6] = dot;
  __syncthreads();
  if (tid == 0) out[row] = red2[0] + red2[1] + red2[2] + red2[3] + bc[0];
}

// =====================================================================
extern "C" void kernel_launch(void* const* d_in, const int* in_sizes, int n_in,
                              void* d_out, int out_size, void* d_ws, size_t ws_size,
                              hipStream_t stream) {
  const float* spatial = (const float*)d_in[0];
  const float* freq    = (const float*)d_in[1];
  const float* Wps   = (const float*)d_in[2];
  const float* bps   = (const float*)d_in[3];
  const float* Wpf   = (const float*)d_in[4];
  const float* bpf   = (const float*)d_in[5];
  // d_in[8], d_in[9], d_in[11], d_in[12] (ca_Wq/ca_Wk/ca_bq/ca_bk) are dead: softmax over 1 key == 1
  const float* pos_s = (const float*)d_in[6];
  const float* pos_f = (const float*)d_in[7];
  const float* ca_Wv = (const float*)d_in[10];
  const float* ca_bv = (const float*)d_in[13];
  const float* ca_Wo = (const float*)d_in[14];
  const float* ca_bo = (const float*)d_in[15];
  const float* n1_g  = (const float*)d_in[16];
  const float* n1_b  = (const float*)d_in[17];
  const float* W1    = (const float*)d_in[18];
  const float* b1    = (const float*)d_in[19];
  const float* W2    = (const float*)d_in[20];
  const float* b2    = (const float*)d_in[21];
  const float* n2_g  = (const float*)d_in[22];
  const float* n2_b  = (const float*)d_in[23];
  const float* sWq   = (const float*)d_in[24];
  const float* sWk   = (const float*)d_in[25];
  const float* sWv   = (const float*)d_in[26];
  const float* sbq   = (const float*)d_in[27];
  const float* sbk   = (const float*)d_in[28];
  const float* sbv   = (const float*)d_in[29];
  const float* sWo   = (const float*)d_in[30];
  const float* sbo   = (const float*)d_in[31];
  const float* n3_g  = (const float*)d_in[32];
  const float* n3_b  = (const float*)d_in[33];
  const float* Wc    = (const float*)d_in[34];
  const float* bc    = (const float*)d_in[35];

  const int Bn = 16384;
  constexpr size_t SZ_BIG = (size_t)16384 * 2048 * 2;   // 64 MiB
  constexpr size_t SZ_ACT = (size_t)16384 * 1024 * 2;   // 32 MiB
  constexpr size_t OFF_S = 0;
  constexpr size_t OFF_A = OFF_S + SZ_BIG;
  constexpr size_t OFF_B = OFF_A + SZ_ACT;   // == 96 MiB
  constexpr size_t OFF_C = OFF_B + SZ_ACT;
  constexpr size_t OFF_D = OFF_C + SZ_ACT;
  constexpr size_t OFF_E = OFF_D + SZ_ACT;
  constexpr size_t OFF_F = OFF_E + SZ_ACT;
  constexpr size_t OFF_W = OFF_F + SZ_ACT;

  uint8_t* ws = (uint8_t*)d_ws;
  u16* S_b  = (u16*)(ws + OFF_S);   // spatial bf16 (later Gb; later qkv[0:96MB))
  u16* F_b  = (u16*)(ws + OFF_A);   // freq bf16
  u16* Qb   = (u16*)(ws + OFF_B);   // (later Hb)
  u16* KVb  = (u16*)(ws + OFF_C);   // live until kv1 GEMM; then Ob
  u16* Vb   = (u16*)(ws + OFF_D);   // (later X2b)
  u16* AOb  = (u16*)(ws + OFF_E);   // (later kv1[0:64MB))
  u16* X1b  = (u16*)(ws + OFF_F);

  u16* wWps = (u16*)(ws + OFF_W);
  u16* wWpf = wWps + (size_t)1024 * 2048;
  u16* wWv  = wWpf + (size_t)1024 * 1024;
  u16* wWo  = wWv  + (size_t)1024 * 1024;
  u16* wW1  = wWo  + (size_t)1024 * 1024;
  u16* wW2  = wW1  + (size_t)2048 * 1024;
  u16* wSq  = wW2  + (size_t)1024 * 2048;   // wSq|wSk|wSv contiguous -> batched N=3072 GEMM
  u16* wSk  = wSq  + (size_t)1024 * 1024;
  u16* wSv  = wSk  + (size_t)1024 * 1024;
  u16* wSo  = wSv  + (size_t)1024 * 1024;
  float* bQKV = (float*)(wSo + (size_t)1024 * 1024);  // 3072 f32: sbq|sbk|sbv
  float* bKV  = bQKV + 3072;                          // 2048 f32: sbk|sbv

  // aliases (phase-based reuse)
  u16* Gb  = (u16*)(ws + OFF_S);
  u16* Hb  = (u16*)(ws + OFF_B);
  u16* X2b = (u16*)(ws + OFF_D);
  u16* qkv = (u16*)(ws + OFF_S);             // [16384][3072] : q0|k0|v0
  u16* kv1 = (u16*)(ws + OFF_E);             // [16384][2048] : k1|v1
  u16* Ob  = (u16*)(ws + OFF_C);
  u16* POb = (u16*)(ws + OFF_S);             // qkv region free after attn2

  auto cvt = [&](const float* src, u16* dst, size_t n) {
    int n4 = (int)(n >> 2);
    cvt_kernel<<<dim3((n4 + 255) / 256), dim3(256), 0, stream>>>(src, dst, n4);
  };
  auto gemm = [&](const u16* A_, const u16* W_, const float* bias, const float* bias2,
                  u16* C_, int N, int K, bool gelu) {
    dim3 grid(128 * (N >> 7));
    if (gelu) gemm_bt<1><<<grid, dim3(256), 0, stream>>>(A_, W_, bias, bias2, C_, N, K);
    else      gemm_bt<0><<<grid, dim3(256), 0, stream>>>(A_, W_, bias, bias2, C_, N, K);
  };

  // 0) convert inputs + weights to bf16; concat self-attn biases (d2d, capture-safe)
  cvt(spatial, S_b, (size_t)Bn * 2048);
  cvt(freq,    F_b, (size_t)Bn * 1024);
  cvt(Wps, wWps, (size_t)1024 * 2048);
  cvt(Wpf, wWpf, (size_t)1024 * 1024);
  cvt(ca_Wv, wWv, (size_t)1024 * 1024);
  cvt(ca_Wo, wWo, (size_t)1024 * 1024);
  cvt(W1, wW1, (size_t)2048 * 1024);
  cvt(W2, wW2, (size_t)1024 * 2048);
  cvt(sWq, wSq, (size_t)1024 * 1024);
  cvt(sWk, wSk, (size_t)1024 * 1024);
  cvt(sWv, wSv, (size_t)1024 * 1024);
  cvt(sWo, wSo, (size_t)1024 * 1024);
  hipMemcpyAsync(bQKV,        sbq, 1024 * sizeof(float), hipMemcpyDeviceToDevice, stream);
  hipMemcpyAsync(bQKV + 1024, sbk, 1024 * sizeof(float), hipMemcpyDeviceToDevice, stream);
  hipMemcpyAsync(bQKV + 2048, sbv, 1024 * sizeof(float), hipMemcpyDeviceToDevice, stream);
  hipMemcpyAsync(bKV,         sbk, 1024 * sizeof(float), hipMemcpyDeviceToDevice, stream);
  hipMemcpyAsync(bKV + 1024,  sbv, 1024 * sizeof(float), hipMemcpyDeviceToDevice, stream);

  // 1) Q = spatial @ Wps^T + bps + pos_s
  gemm(S_b, wWps, bps, pos_s, Qb, 1024, 2048, false);
  // 2) KV = freq @ Wpf^T + bpf + pos_f
  gemm(F_b, wWpf, bpf, pos_f, KVb, 1024, 1024, false);
  // 3) V = KV @ ca_Wv^T + ca_bv ; 4) AO = V @ ca_Wo^T + ca_bo  (cross-attn collapsed)
  gemm(KVb, wWv, ca_bv, nullptr, Vb, 1024, 1024, false);
  gemm(Vb, wWo, ca_bo, nullptr, AOb, 1024, 1024, false);
  // 5) X1 = LN(Q + AO)
  ln_res<<<dim3(Bn), dim3(256), 0, stream>>>(Qb, AOb, n1_g, n1_b, X1b);
  // 6) G = gelu(X1 @ W1^T + b1) ; 7) H = G @ W2^T + b2
  gemm(X1b, wW1, b1, nullptr, Gb, 2048, 1024, true);
  gemm(Gb, wW2, b2, nullptr, Hb, 1024, 2048, false);
  // 8) X2 = LN(X1 + H)
  ln_res<<<dim3(Bn), dim3(256), 0, stream>>>(X1b, Hb, n2_g, n2_b, X2b);
  // 9) [q0|k0|v0] = X2 @ [Wq|Wk|Wv]^T  (batched, N=3072)
  gemm(X2b, wSq, bQKV, nullptr, qkv, 3072, 1024, false);
  // 10) [k1|v1] = KV @ [Wk|Wv]^T  (batched, N=2048)
  gemm(KVb, wSk, bKV, nullptr, kv1, 2048, 1024, false);
  // 11) 2-key attention combine per head
  attn2<<<dim3(Bn), dim3(256), 0, stream>>>(qkv, qkv + 1024, qkv + 2048, 3072,
                                            kv1, kv1 + 1024, 2048, Ob);
  // 12) PO = O @ sa_Wo^T + sa_bo
  gemm(Ob, wSo, sbo, nullptr, POb, 1024, 1024, false);
  // 13) out = LN(X2 + PO; n3) . Wc + bc
  final_k<<<dim3(Bn), dim3(256), 0, stream>>>(X2b, POb, n3_g, n3_b, Wc, bc, (float*)d_out);
}

// Round 3
// 945.203 us; speedup vs baseline: 1.1802x; 1.0960x over previous
//
#include <hip/hip_runtime.h>
#include <hip/hip_bf16.h>
#include <cstdint>
#include <cstddef>

typedef unsigned short u16;
typedef __bf16 bf16x8 __attribute__((ext_vector_type(8)));
typedef float f32x4 __attribute__((ext_vector_type(4)));

#define GLOBAL_AS(p) ((const __attribute__((address_space(1))) void*)(p))
#define LDS_AS(p)    ((__attribute__((address_space(3))) void*)(p))

__device__ __forceinline__ float b2f(u16 u) {
  return __builtin_bit_cast(float, (unsigned)u << 16);
}
__device__ __forceinline__ u16 f2b(float f) {
  unsigned u = __builtin_bit_cast(unsigned, f);
  u += 0x7FFFu + ((u >> 16) & 1u);   // round-to-nearest-even
  return (u16)(u >> 16);
}

// ---------------- f32 -> bf16 convert (4 elems/thread) ----------------
__global__ __launch_bounds__(256) void cvt_kernel(const float* __restrict__ src,
                                                  u16* __restrict__ dst, int n4) {
  int i = blockIdx.x * 256 + threadIdx.x;
  if (i < n4) {
    float4 f = ((const float4*)src)[i];
    ushort4 o;
    o.x = f2b(f.x); o.y = f2b(f.y); o.z = f2b(f.z); o.w = f2b(f.w);
    ((ushort4*)dst)[i] = o;
  }
}

// ---------------- 256x256 GEMM, BK=64, 8 waves, dbuf LDS + counted vmcnt + swizzle ----
// C(bf16, MxN) = A(bf16, MxK) @ W(bf16, NxK)^T + bias [+bias2] [gelu]
// LDS: 2 buffers x (A 256x64 + B 256x64) bf16 = 128 KiB.
// Swizzle (T2): LDS[row][c] holds Data[row][c ^ ((row&7)<<3)]; DMA dest linear,
// per-lane global SOURCE pre-permuted (involution), ds_read applies same XOR (rule #21).
template<int EPI>  // 0 = none, 1 = exact gelu
__global__ __launch_bounds__(512, 2)
void gemm256(const u16* __restrict__ A, const u16* __restrict__ W,
             const float* __restrict__ bias, const float* __restrict__ bias2,
             u16* __restrict__ C, int N, int K, int nTn)
{
  __shared__ alignas(16) u16 LDS[65536];   // 128 KiB
  const int tid  = threadIdx.x;
  const int lane = tid & 63;
  const int wave = tid >> 6;

  // T1: XCD-chunked bijective swizzle (gridDim.x % 8 == 0 for all our shapes)
  const int bq = (int)gridDim.x >> 3;
  const int t  = ((int)blockIdx.x & 7) * bq + ((int)blockIdx.x >> 3);
  const int bm = t / nTn, bn = t % nTn;
  const size_t row0 = (size_t)bm << 8;
  const int col0 = bn << 8;

  // ---- staging geometry: per wave 4 insts/matrix, inst covers 8 rows x 64 cols (1 KiB)
  // dest (linear): row = wave*32 + i*8 + (lane>>3), colByte = (lane&7)*16
  // source col pre-swizzled: colElem = ((lane&7) ^ ((lane>>3)&7)) * 8
  const int stRow = (wave << 5) + (lane >> 3);
  const int stCol = (((lane & 7) ^ ((lane >> 3) & 7)) << 3);
  const u16* gA = A + ((size_t)(row0 + stRow)) * K + stCol;
  const u16* gB = W + ((size_t)(col0 + stRow)) * K + stCol;
  const int stBase = wave << 11;           // wave*2048 u16 (4 KiB)

  // ---- fragment read geometry
  const int wm = wave >> 2;                // 0..1  -> 128-row half
  const int wn = wave & 3;                 // 0..3  -> 64-col quarter
  const int frA = lane & 15;
  const int kq  = lane >> 4;               // 0..3
  const int sx  = (lane & 7) << 3;         // swizzle XOR in elems
  const int colE0 = (kq << 3) ^ sx;        // kk=0
  const int colE1 = (32 + (kq << 3)) ^ sx; // kk=1
  const int aRow = wm * 128 + frA;
  const int bRow = wn * 64 + frA;

  const int NT = K >> 6;

  auto STAGE = [&](int kt, int buf) {
    const size_t ko = (size_t)kt << 6;
    u16* la = LDS + buf * 32768 + stBase;
    u16* lb = la + 16384;
    const u16* ga = gA + ko;
    const u16* gb = gB + ko;
#pragma unroll
    for (int i = 0; i < 4; ++i)
      __builtin_amdgcn_global_load_lds(GLOBAL_AS(ga + (size_t)i * 8 * K), LDS_AS(la + i * 512), 16, 0, 0);
#pragma unroll
    for (int i = 0; i < 4; ++i)
      __builtin_amdgcn_global_load_lds(GLOBAL_AS(gb + (size_t)i * 8 * K), LDS_AS(lb + i * 512), 16, 0, 0);
  };

  f32x4 acc[8][4];
  {
    f32x4 z = {0.f, 0.f, 0.f, 0.f};
#pragma unroll
    for (int m = 0; m < 8; ++m)
#pragma unroll
      for (int n = 0; n < 4; ++n) acc[m][n] = z;
  }

  STAGE(0, 0);   // prologue: K-tile 0 -> buf0 (8 DMA loads/wave in flight)

  for (int kt = 0; kt < NT; ++kt) {
    const int buf = kt & 1;
    if (kt + 1 < NT) {
      STAGE(kt + 1, buf ^ 1);                                   // 16 in flight
      asm volatile("s_waitcnt vmcnt(8)" ::: "memory");          // kt's 8 landed (T4: counted, never 0)
    } else {
      asm volatile("s_waitcnt vmcnt(0)" ::: "memory");
    }
    __syncthreads();                                            // all waves' DMA visible

    const u16* la = LDS + buf * 32768;
    const u16* lb = la + 16384;
#pragma unroll
    for (int kk = 0; kk < 2; ++kk) {
      const int ce = kk ? colE1 : colE0;
      bf16x8 af[8], bfb[4];
#pragma unroll
      for (int m = 0; m < 8; ++m) af[m]  = *(const bf16x8*)(la + (aRow + m * 16) * 64 + ce);
#pragma unroll
      for (int n = 0; n < 4; ++n) bfb[n] = *(const bf16x8*)(lb + (bRow + n * 16) * 64 + ce);
#pragma unroll
      for (int m = 0; m < 8; ++m)
#pragma unroll
        for (int n = 0; n < 4; ++n)
          acc[m][n] = __builtin_amdgcn_mfma_f32_16x16x32_bf16(af[m], bfb[n], acc[m][n], 0, 0, 0);
    }
    __syncthreads();   // reads of buf done -> next DMA may overwrite it
  }

  // epilogue: C/D layout col=lane&15, row=(lane>>4)*4+r
  const int orow = kq << 2;
#pragma unroll
  for (int n = 0; n < 4; ++n) {
    const int gcol = col0 + wn * 64 + n * 16 + frA;
    float bb = 0.f;
    if (bias)  bb += bias[gcol];
    if (bias2) bb += bias2[gcol];
#pragma unroll
    for (int m = 0; m < 8; ++m) {
#pragma unroll
      for (int r = 0; r < 4; ++r) {
        const size_t grow = row0 + wm * 128 + m * 16 + orow + r;
        float v = acc[m][n][r] + bb;
        if (EPI == 1) v = 0.5f * v * (1.f + erff(v * 0.70710678118654752f));
        C[grow * N + gcol] = f2b(v);
      }
    }
  }
}

// ---------------- LayerNorm of residual sum: O = LN(X + Y) * g + b, row width 1024 ----
__global__ __launch_bounds__(256)
void ln_res(const u16* __restrict__ X, const u16* __restrict__ Y,
            const float* __restrict__ g, const float* __restrict__ bta,
            u16* __restrict__ O)
{
  const int row = blockIdx.x;
  const int tid = threadIdx.x;
  const size_t base = (size_t)row * 1024 + tid * 4;
  ushort4 xv = *(const ushort4*)(X + base);
  ushort4 yv = *(const ushort4*)(Y + base);
  float v0 = b2f(xv.x) + b2f(yv.x);
  float v1 = b2f(xv.y) + b2f(yv.y);
  float v2 = b2f(xv.z) + b2f(yv.z);
  float v3 = b2f(xv.w) + b2f(yv.w);
  float s  = v0 + v1 + v2 + v3;
  float ss = v0*v0 + v1*v1 + v2*v2 + v3*v3;
#pragma unroll
  for (int off = 32; off; off >>= 1) {
    s  += __shfl_down(s, off);
    ss += __shfl_down(ss, off);
  }
  __shared__ float red[8];
  if ((tid & 63) == 0) { red[tid >> 6] = s; red[4 + (tid >> 6)] = ss; }
  __syncthreads();
  const float S  = red[0] + red[1] + red[2] + red[3];
  const float SS = red[4] + red[5] + red[6] + red[7];
  const float mu  = S * (1.f / 1024.f);
  const float inv = rsqrtf(SS * (1.f / 1024.f) - mu * mu + 1e-5f);
  const int n = tid * 4;
  float4 gv = *(const float4*)(g + n);
  float4 bv = *(const float4*)(bta + n);
  ushort4 o;
  o.x = f2b((v0 - mu) * inv * gv.x + bv.x);
  o.y = f2b((v1 - mu) * inv * gv.y + bv.y);
  o.z = f2b((v2 - mu) * inv * gv.z + bv.z);
  o.w = f2b((v3 - mu) * inv * gv.w + bv.w);
  *(ushort4*)(O + base) = o;
}

// ---------------- 2-key attention combine, 8 heads of d=128 (strided inputs) ----------------
__global__ __launch_bounds__(256)
void attn2(const u16* __restrict__ Q, const u16* __restrict__ K0, const u16* __restrict__ V0, int sQ,
           const u16* __restrict__ K1, const u16* __restrict__ V1, int sK,
           u16* __restrict__ O)
{
  const int row = blockIdx.x;
  const int tid = threadIdx.x;
  const size_t bq = (size_t)row * sQ + tid * 4;
  const size_t bk = (size_t)row * sK + tid * 4;
  const size_t bo = (size_t)row * 1024 + tid * 4;
  ushort4 qv  = *(const ushort4*)(Q  + bq);
  ushort4 k0v = *(const ushort4*)(K0 + bq);
  ushort4 v0v = *(const ushort4*)(V0 + bq);
  ushort4 k1v = *(const ushort4*)(K1 + bk);
  ushort4 v1v = *(const ushort4*)(V1 + bk);
  float q0 = b2f(qv.x), q1 = b2f(qv.y), q2 = b2f(qv.z), q3 = b2f(qv.w);
  float d0 = q0*b2f(k0v.x) + q1*b2f(k0v.y) + q2*b2f(k0v.z) + q3*b2f(k0v.w);
  float d1 = q0*b2f(k1v.x) + q1*b2f(k1v.y) + q2*b2f(k1v.z) + q3*b2f(k1v.w);
#pragma unroll
  for (int off = 16; off; off >>= 1) {
    d0 += __shfl_xor(d0, off);
    d1 += __shfl_xor(d1, off);
  }
  const float sc = 0.088388347648318447f;  // 1/sqrt(128)
  float s0 = d0 * sc, s1 = d1 * sc;
  float mx = fmaxf(s0, s1);
  float e0 = expf(s0 - mx), e1 = expf(s1 - mx);
  float r = 1.f / (e0 + e1);
  float a0 = e0 * r, a1 = e1 * r;
  ushort4 o;
  o.x = f2b(a0 * b2f(v0v.x) + a1 * b2f(v1v.x));
  o.y = f2b(a0 * b2f(v0v.y) + a1 * b2f(v1v.y));
  o.z = f2b(a0 * b2f(v0v.z) + a1 * b2f(v1v.z));
  o.w = f2b(a0 * b2f(v0v.w) + a1 * b2f(v1v.w));
  *(ushort4*)(O + bo) = o;
}

// ---------------- final: out[row] = dot(LN(X + Y)*g + b, Wc) + bc ----------------
__global__ __launch_bounds__(256)
void final_k(const u16* __restrict__ X, const u16* __restrict__ Y,
             const float* __restrict__ g, const float* __restrict__ bta,
             const float* __restrict__ Wc, const float* __restrict__ bc,
             float* __restrict__ out)
{
  const int row = blockIdx.x;
  const int tid = threadIdx.x;
  const size_t base = (size_t)row * 1024 + tid * 4;
  ushort4 xv = *(const ushort4*)(X + base);
  ushort4 yv = *(const ushort4*)(Y + base);
  float v0 = b2f(xv.x) + b2f(yv.x);
  float v1 = b2f(xv.y) + b2f(yv.y);
  float v2 = b2f(xv.z) + b2f(yv.z);
  float v3 = b2f(xv.w) + b2f(yv.w);
  float s  = v0 + v1 + v2 + v3;
  float ss = v0*v0 + v1*v1 + v2*v2 + v3*v3;
#pragma unroll
  for (int off = 32; off; off >>= 1) {
    s  += __shfl_down(s, off);
    ss += __shfl_down(ss, off);
  }
  __shared__ float red[8];
  __shared__ float red2[4];
  if ((tid & 63) == 0) { red[tid >> 6] = s; red[4 + (tid >> 6)] = ss; }
  __syncthreads();
  const float S  = red[0] + red[1] + red[2] + red[3];
  const float SS = red[4] + red[5] + red[6] + red[7];
  const float mu  = S * (1.f / 1024.f);
  const float inv = rsqrtf(SS * (1.f / 1024.f) - mu * mu + 1e-5f);
  const int n = tid * 4;
  float4 gv = *(const float4*)(g + n);
  float4 bv = *(const float4*)(bta + n);
  float4 wv = *(const float4*)(Wc + n);
  float dot = ((v0 - mu) * inv * gv.x + bv.x) * wv.x
            + ((v1 - mu) * inv * gv.y + bv.y) * wv.y
            + ((v2 - mu) * inv * gv.z + bv.z) * wv.z
            + ((v3 - mu) * inv * gv.w + bv.w) * wv.w;
#pragma unroll
  for (int off = 32; off; off >>= 1) dot += __shfl_down(dot, off);
  if ((tid & 63) == 0) red2[tid >> 6] = dot;
  __syncthreads();
  if (tid == 0) out[row] = red2[0] + red2[1] + red2[2] + red2[3] + bc[0];
}

// =====================================================================
extern "C" void kernel_launch(void* const* d_in, const int* in_sizes, int n_in,
                              void* d_out, int out_size, void* d_ws, size_t ws_size,
                              hipStream_t stream) {
  const float* spatial = (const float*)d_in[0];
  const float* freq    = (const float*)d_in[1];
  const float* Wps   = (const float*)d_in[2];
  const float* bps   = (const float*)d_in[3];
  const float* Wpf   = (const float*)d_in[4];
  const float* bpf   = (const float*)d_in[5];
  // d_in[8], d_in[9], d_in[11], d_in[12] (ca_Wq/ca_Wk/ca_bq/ca_bk) are dead: softmax over 1 key == 1
  const float* pos_s = (const float*)d_in[6];
  const float* pos_f = (const float*)d_in[7];
  const float* ca_Wv = (const float*)d_in[10];
  const float* ca_bv = (const float*)d_in[13];
  const float* ca_Wo = (const float*)d_in[14];
  const float* ca_bo = (const float*)d_in[15];
  const float* n1_g  = (const float*)d_in[16];
  const float* n1_b  = (const float*)d_in[17];
  const float* W1    = (const float*)d_in[18];
  const float* b1    = (const float*)d_in[19];
  const float* W2    = (const float*)d_in[20];
  const float* b2    = (const float*)d_in[21];
  const float* n2_g  = (const float*)d_in[22];
  const float* n2_b  = (const float*)d_in[23];
  const float* sWq   = (const float*)d_in[24];
  const float* sWk   = (const float*)d_in[25];
  const float* sWv   = (const float*)d_in[26];
  const float* sbq   = (const float*)d_in[27];
  const float* sbk   = (const float*)d_in[28];
  const float* sbv   = (const float*)d_in[29];
  const float* sWo   = (const float*)d_in[30];
  const float* sbo   = (const float*)d_in[31];
  const float* n3_g  = (const float*)d_in[32];
  const float* n3_b  = (const float*)d_in[33];
  const float* Wc    = (const float*)d_in[34];
  const float* bc    = (const float*)d_in[35];

  const int Bn = 16384;
  constexpr size_t SZ_BIG = (size_t)16384 * 2048 * 2;   // 64 MiB
  constexpr size_t SZ_ACT = (size_t)16384 * 1024 * 2;   // 32 MiB
  constexpr size_t OFF_S = 0;
  constexpr size_t OFF_A = OFF_S + SZ_BIG;
  constexpr size_t OFF_B = OFF_A + SZ_ACT;   // == 96 MiB
  constexpr size_t OFF_C = OFF_B + SZ_ACT;
  constexpr size_t OFF_D = OFF_C + SZ_ACT;
  constexpr size_t OFF_E = OFF_D + SZ_ACT;
  constexpr size_t OFF_F = OFF_E + SZ_ACT;
  constexpr size_t OFF_W = OFF_F + SZ_ACT;

  uint8_t* ws = (uint8_t*)d_ws;
  u16* S_b  = (u16*)(ws + OFF_S);   // spatial bf16 (later Gb; later qkv[0:96MB))
  u16* F_b  = (u16*)(ws + OFF_A);   // freq bf16
  u16* Qb   = (u16*)(ws + OFF_B);   // (later Hb)
  u16* KVb  = (u16*)(ws + OFF_C);   // live until kv1 GEMM; then Ob
  u16* Vb   = (u16*)(ws + OFF_D);   // (later X2b)
  u16* AOb  = (u16*)(ws + OFF_E);   // (later kv1[0:64MB))
  u16* X1b  = (u16*)(ws + OFF_F);

  u16* wWps = (u16*)(ws + OFF_W);
  u16* wWpf = wWps + (size_t)1024 * 2048;
  u16* wWv  = wWpf + (size_t)1024 * 1024;
  u16* wWo  = wWv  + (size_t)1024 * 1024;
  u16* wW1  = wWo  + (size_t)1024 * 1024;
  u16* wW2  = wW1  + (size_t)2048 * 1024;
  u16* wSq  = wW2  + (size_t)1024 * 2048;   // wSq|wSk|wSv contiguous -> batched N=3072 GEMM
  u16* wSk  = wSq  + (size_t)1024 * 1024;
  u16* wSv  = wSk  + (size_t)1024 * 1024;
  u16* wSo  = wSv  + (size_t)1024 * 1024;
  float* bQKV = (float*)(wSo + (size_t)1024 * 1024);  // 3072 f32: sbq|sbk|sbv
  float* bKV  = bQKV + 3072;                          // 2048 f32: sbk|sbv

  // aliases (phase-based reuse)
  u16* Gb  = (u16*)(ws + OFF_S);
  u16* Hb  = (u16*)(ws + OFF_B);
  u16* X2b = (u16*)(ws + OFF_D);
  u16* qkv = (u16*)(ws + OFF_S);             // [16384][3072] : q0|k0|v0
  u16* kv1 = (u16*)(ws + OFF_E);             // [16384][2048] : k1|v1
  u16* Ob  = (u16*)(ws + OFF_C);
  u16* POb = (u16*)(ws + OFF_S);             // qkv region free after attn2

  auto cvt = [&](const float* src, u16* dst, size_t n) {
    int n4 = (int)(n >> 2);
    cvt_kernel<<<dim3((n4 + 255) / 256), dim3(256), 0, stream>>>(src, dst, n4);
  };
  auto gemm = [&](const u16* A_, const u16* W_, const float* bias, const float* bias2,
                  u16* C_, int N, int K, bool gelu) {
    const int nTn = N >> 8;
    dim3 grid(64 * nTn);   // (16384/256) * (N/256); always % 8 == 0
    if (gelu) gemm256<1><<<grid, dim3(512), 0, stream>>>(A_, W_, bias, bias2, C_, N, K, nTn);
    else      gemm256<0><<<grid, dim3(512), 0, stream>>>(A_, W_, bias, bias2, C_, N, K, nTn);
  };

  // 0) convert inputs + weights to bf16; concat self-attn biases (d2d, capture-safe)
  cvt(spatial, S_b, (size_t)Bn * 2048);
  cvt(freq,    F_b, (size_t)Bn * 1024);
  cvt(Wps, wWps, (size_t)1024 * 2048);
  cvt(Wpf, wWpf, (size_t)1024 * 1024);
  cvt(ca_Wv, wWv, (size_t)1024 * 1024);
  cvt(ca_Wo, wWo, (size_t)1024 * 1024);
  cvt(W1, wW1, (size_t)2048 * 1024);
  cvt(W2, wW2, (size_t)1024 * 2048);
  cvt(sWq, wSq, (size_t)1024 * 1024);
  cvt(sWk, wSk, (size_t)1024 * 1024);
  cvt(sWv, wSv, (size_t)1024 * 1024);
  cvt(sWo, wSo, (size_t)1024 * 1024);
  hipMemcpyAsync(bQKV,        sbq, 1024 * sizeof(float), hipMemcpyDeviceToDevice, stream);
  hipMemcpyAsync(bQKV + 1024, sbk, 1024 * sizeof(float), hipMemcpyDeviceToDevice, stream);
  hipMemcpyAsync(bQKV + 2048, sbv, 1024 * sizeof(float), hipMemcpyDeviceToDevice, stream);
  hipMemcpyAsync(bKV,         sbk, 1024 * sizeof(float), hipMemcpyDeviceToDevice, stream);
  hipMemcpyAsync(bKV + 1024,  sbv, 1024 * sizeof(float), hipMemcpyDeviceToDevice, stream);

  // 1) Q = spatial @ Wps^T + bps + pos_s
  gemm(S_b, wWps, bps, pos_s, Qb, 1024, 2048, false);
  // 2) KV = freq @ Wpf^T + bpf + pos_f
  gemm(F_b, wWpf, bpf, pos_f, KVb, 1024, 1024, false);
  // 3) V = KV @ ca_Wv^T + ca_bv ; 4) AO = V @ ca_Wo^T + ca_bo  (cross-attn collapsed)
  gemm(KVb, wWv, ca_bv, nullptr, Vb, 1024, 1024, false);
  gemm(Vb, wWo, ca_bo, nullptr, AOb, 1024, 1024, false);
  // 5) X1 = LN(Q + AO)
  ln_res<<<dim3(Bn), dim3(256), 0, stream>>>(Qb, AOb, n1_g, n1_b, X1b);
  // 6) G = gelu(X1 @ W1^T + b1) ; 7) H = G @ W2^T + b2
  gemm(X1b, wW1, b1, nullptr, Gb, 2048, 1024, true);
  gemm(Gb, wW2, b2, nullptr, Hb, 1024, 2048, false);
  // 8) X2 = LN(X1 + H)
  ln_res<<<dim3(Bn), dim3(256), 0, stream>>>(X1b, Hb, n2_g, n2_b, X2b);
  // 9) [q0|k0|v0] = X2 @ [Wq|Wk|Wv]^T  (batched, N=3072)
  gemm(X2b, wSq, bQKV, nullptr, qkv, 3072, 1024, false);
  // 10) [k1|v1] = KV @ [Wk|Wv]^T  (batched, N=2048)
  gemm(KVb, wSk, bKV, nullptr, kv1, 2048, 1024, false);
  // 11) 2-key attention combine per head
  attn2<<<dim3(Bn), dim3(256), 0, stream>>>(qkv, qkv + 1024, qkv + 2048, 3072,
                                            kv1, kv1 + 1024, 2048, Ob);
  // 12) PO = O @ sa_Wo^T + sa_bo
  gemm(Ob, wSo, sbo, nullptr, POb, 1024, 1024, false);
  // 13) out = LN(X2 + PO; n3) . Wc + bc
  final_k<<<dim3(Bn), dim3(256), 0, stream>>>(X2b, POb, n3_g, n3_b, Wc, bc, (float*)d_out);
}

// Round 4
// 749.034 us; speedup vs baseline: 1.4892x; 1.2619x over previous
//
#include <hip/hip_runtime.h>
#include <hip/hip_bf16.h>
#include <cstdint>
#include <cstddef>

typedef unsigned short u16;
typedef __bf16 bf16x8 __attribute__((ext_vector_type(8)));
typedef float f32x4 __attribute__((ext_vector_type(4)));

#define GLOBAL_AS(p) ((const __attribute__((address_space(1))) void*)(p))
#define LDS_AS(p)    ((__attribute__((address_space(3))) void*)(p))

__device__ __forceinline__ float b2f(u16 u) {
  return __builtin_bit_cast(float, (unsigned)u << 16);
}
__device__ __forceinline__ u16 f2b(float f) {
  unsigned u = __builtin_bit_cast(unsigned, f);
  u += 0x7FFFu + ((u >> 16) & 1u);   // round-to-nearest-even
  return (u16)(u >> 16);
}

// ---------------- f32 -> bf16 convert (4 elems/thread) ----------------
__global__ __launch_bounds__(256) void cvt_kernel(const float* __restrict__ src,
                                                  u16* __restrict__ dst, int n4) {
  int i = blockIdx.x * 256 + threadIdx.x;
  if (i < n4) {
    float4 f = ((const float4*)src)[i];
    ushort4 o;
    o.x = f2b(f.x); o.y = f2b(f.y); o.z = f2b(f.z); o.w = f2b(f.w);
    ((ushort4*)dst)[i] = o;
  }
}

// ---------------- 256x256 GEMM, BK=64, 8 waves; T3 min-2-phase + T2 swizzle + T1 ----
// C(bf16, MxN) = A(bf16, MxK) @ W(bf16, NxK)^T + bias [+bias2] [gelu]
// Main loop LDS: 2 buffers x (A 256x64 + B 256x64) bf16 = 128 KiB (first 65536 u16).
// Raw s_barrier (NOT __syncthreads -> no implicit vmcnt(0) drain); STAGE(t+1) issued
// BEFORE compute(t); single vmcnt(0)+barrier per K-tile AFTER compute (T3 recipe).
// Swizzle (T2): LDS[row][c] holds Data[row][c ^ ((row&7)<<3)]; DMA dest linear,
// per-lane global SOURCE pre-permuted (involution), ds_read applies same XOR.
// Epilogue: wave-private LDS transpose (128x68 u16, padded) -> 16B coalesced stores.
template<int EPI>  // 0 = none, 1 = exact gelu
__global__ __launch_bounds__(512, 2)
void gemm256(const u16* __restrict__ A, const u16* __restrict__ W,
             const float* __restrict__ bias, const float* __restrict__ bias2,
             u16* __restrict__ C, int N, int K, int nTn)
{
  __shared__ alignas(16) u16 LDS[69632];   // 136 KiB (main loop uses 128 KiB)
  const int tid  = threadIdx.x;
  const int lane = tid & 63;
  const int wave = tid >> 6;

  // T1: XCD-chunked bijective swizzle (gridDim.x % 8 == 0 for all our shapes)
  const int bq = (int)gridDim.x >> 3;
  const int t  = ((int)blockIdx.x & 7) * bq + ((int)blockIdx.x >> 3);
  const int bm = t / nTn, bn = t % nTn;
  const size_t row0 = (size_t)bm << 8;
  const int col0 = bn << 8;

  // ---- staging geometry: per wave 4 insts/matrix, inst covers 8 rows x 64 cols (1 KiB)
  // dest (linear): row = wave*32 + i*8 + (lane>>3), colByte = (lane&7)*16
  // source col pre-swizzled: colElem = ((lane&7) ^ ((lane>>3)&7)) * 8
  const int stRow = (wave << 5) + (lane >> 3);
  const int stCol = (((lane & 7) ^ ((lane >> 3) & 7)) << 3);
  const u16* gA = A + ((size_t)(row0 + stRow)) * K + stCol;
  const u16* gB = W + ((size_t)(col0 + stRow)) * K + stCol;
  const int stBase = wave << 11;           // wave*2048 u16 (4 KiB)

  // ---- fragment read geometry
  const int wm = wave >> 2;                // 0..1  -> 128-row half
  const int wn = wave & 3;                 // 0..3  -> 64-col quarter
  const int frA = lane & 15;
  const int kq  = lane >> 4;               // 0..3
  const int sx  = (lane & 7) << 3;         // swizzle XOR in elems
  const int colE0 = (kq << 3) ^ sx;        // kk=0
  const int colE1 = (32 + (kq << 3)) ^ sx; // kk=1
  const int aRow = wm * 128 + frA;
  const int bRow = wn * 64 + frA;

  const int NT = K >> 6;

  auto STAGE = [&](int kt, int buf) {
    const size_t ko = (size_t)kt << 6;
    u16* la = LDS + buf * 32768 + stBase;
    u16* lb = la + 16384;
    const u16* ga = gA + ko;
    const u16* gb = gB + ko;
#pragma unroll
    for (int i = 0; i < 4; ++i)
      __builtin_amdgcn_global_load_lds(GLOBAL_AS(ga + (size_t)i * 8 * K), LDS_AS(la + i * 512), 16, 0, 0);
#pragma unroll
    for (int i = 0; i < 4; ++i)
      __builtin_amdgcn_global_load_lds(GLOBAL_AS(gb + (size_t)i * 8 * K), LDS_AS(lb + i * 512), 16, 0, 0);
  };

  f32x4 acc[8][4];
  {
    f32x4 z = {0.f, 0.f, 0.f, 0.f};
#pragma unroll
    for (int m = 0; m < 8; ++m)
#pragma unroll
      for (int n = 0; n < 4; ++n) acc[m][n] = z;
  }

  // prologue: tile 0 -> buf0, drain, align
  STAGE(0, 0);
  asm volatile("s_waitcnt vmcnt(0)" ::: "memory");
  __builtin_amdgcn_s_barrier();

  for (int kt = 0; kt < NT; ++kt) {
    const int buf = kt & 1;
    if (kt + 1 < NT) STAGE(kt + 1, buf ^ 1);   // issue prefetch BEFORE compute (T3)

    const u16* la = LDS + buf * 32768;
    const u16* lb = la + 16384;
    __builtin_amdgcn_s_setprio(1);
#pragma unroll
    for (int kk = 0; kk < 2; ++kk) {
      const int ce = kk ? colE1 : colE0;
      bf16x8 af[8], bfb[4];
#pragma unroll
      for (int m = 0; m < 8; ++m) af[m]  = *(const bf16x8*)(la + (aRow + m * 16) * 64 + ce);
#pragma unroll
      for (int n = 0; n < 4; ++n) bfb[n] = *(const bf16x8*)(lb + (bRow + n * 16) * 64 + ce);
#pragma unroll
      for (int m = 0; m < 8; ++m)
#pragma unroll
        for (int n = 0; n < 4; ++n)
          acc[m][n] = __builtin_amdgcn_mfma_f32_16x16x32_bf16(af[m], bfb[n], acc[m][n], 0, 0, 0);
    }
    __builtin_amdgcn_s_setprio(0);
    // prefetch had the whole compute phase to land; counted drain once per K-tile
    asm volatile("s_waitcnt vmcnt(0)" ::: "memory");
    __builtin_amdgcn_s_barrier();
  }

  // ---- epilogue: wave-private LDS transpose -> coalesced 16B stores ----
  // (last-iteration barrier above guarantees all waves finished reading the buffers)
  u16* Wl = LDS + wave * 8704;                 // 128 x 68 u16 (pad 4 breaks kq-bank overlap)
  const int orow = kq << 2;
#pragma unroll
  for (int n = 0; n < 4; ++n) {
    const int gcol = col0 + wn * 64 + n * 16 + frA;
    float bb = 0.f;
    if (bias)  bb += bias[gcol];
    if (bias2) bb += bias2[gcol];
#pragma unroll
    for (int m = 0; m < 8; ++m) {
#pragma unroll
      for (int r = 0; r < 4; ++r) {
        float v = acc[m][n][r] + bb;
        if (EPI == 1) v = 0.5f * v * (1.f + erff(v * 0.70710678118654752f));
        Wl[(m * 16 + orow + r) * 68 + n * 16 + frA] = f2b(v);
      }
    }
  }
  asm volatile("s_waitcnt lgkmcnt(0)" ::: "memory");   // wave-private: no barrier needed
#pragma unroll
  for (int p = 0; p < 16; ++p) {
    const int row = p * 8 + (lane >> 3);
    const int cu  = (lane & 7) << 3;
    bf16x8 v = *(const bf16x8*)(Wl + row * 68 + cu);
    *(bf16x8*)(&C[(row0 + wm * 128 + row) * N + col0 + wn * 64 + cu]) = v;
  }
}

// ---------------- LayerNorm of residual sum: O = LN(X + Y) * g + b, row width 1024 ----
__global__ __launch_bounds__(256)
void ln_res(const u16* __restrict__ X, const u16* __restrict__ Y,
            const float* __restrict__ g, const float* __restrict__ bta,
            u16* __restrict__ O)
{
  const int row = blockIdx.x;
  const int tid = threadIdx.x;
  const size_t base = (size_t)row * 1024 + tid * 4;
  ushort4 xv = *(const ushort4*)(X + base);
  ushort4 yv = *(const ushort4*)(Y + base);
  float v0 = b2f(xv.x) + b2f(yv.x);
  float v1 = b2f(xv.y) + b2f(yv.y);
  float v2 = b2f(xv.z) + b2f(yv.z);
  float v3 = b2f(xv.w) + b2f(yv.w);
  float s  = v0 + v1 + v2 + v3;
  float ss = v0*v0 + v1*v1 + v2*v2 + v3*v3;
#pragma unroll
  for (int off = 32; off; off >>= 1) {
    s  += __shfl_down(s, off);
    ss += __shfl_down(ss, off);
  }
  __shared__ float red[8];
  if ((tid & 63) == 0) { red[tid >> 6] = s; red[4 + (tid >> 6)] = ss; }
  __syncthreads();
  const float S  = red[0] + red[1] + red[2] + red[3];
  const float SS = red[4] + red[5] + red[6] + red[7];
  const float mu  = S * (1.f / 1024.f);
  const float inv = rsqrtf(SS * (1.f / 1024.f) - mu * mu + 1e-5f);
  const int n = tid * 4;
  float4 gv = *(const float4*)(g + n);
  float4 bv = *(const float4*)(bta + n);
  ushort4 o;
  o.x = f2b((v0 - mu) * inv * gv.x + bv.x);
  o.y = f2b((v1 - mu) * inv * gv.y + bv.y);
  o.z = f2b((v2 - mu) * inv * gv.z + bv.z);
  o.w = f2b((v3 - mu) * inv * gv.w + bv.w);
  *(ushort4*)(O + base) = o;
}

// ---------------- 2-key attention combine, 8 heads of d=128 (strided inputs) ----------------
__global__ __launch_bounds__(256)
void attn2(const u16* __restrict__ Q, const u16* __restrict__ K0, const u16* __restrict__ V0, int sQ,
           const u16* __restrict__ K1, const u16* __restrict__ V1, int sK,
           u16* __restrict__ O)
{
  const int row = blockIdx.x;
  const int tid = threadIdx.x;
  const size_t bq = (size_t)row * sQ + tid * 4;
  const size_t bk = (size_t)row * sK + tid * 4;
  const size_t bo = (size_t)row * 1024 + tid * 4;
  ushort4 qv  = *(const ushort4*)(Q  + bq);
  ushort4 k0v = *(const ushort4*)(K0 + bq);
  ushort4 v0v = *(const ushort4*)(V0 + bq);
  ushort4 k1v = *(const ushort4*)(K1 + bk);
  ushort4 v1v = *(const ushort4*)(V1 + bk);
  float q0 = b2f(qv.x), q1 = b2f(qv.y), q2 = b2f(qv.z), q3 = b2f(qv.w);
  float d0 = q0*b2f(k0v.x) + q1*b2f(k0v.y) + q2*b2f(k0v.z) + q3*b2f(k0v.w);
  float d1 = q0*b2f(k1v.x) + q1*b2f(k1v.y) + q2*b2f(k1v.z) + q3*b2f(k1v.w);
#pragma unroll
  for (int off = 16; off; off >>= 1) {
    d0 += __shfl_xor(d0, off);
    d1 += __shfl_xor(d1, off);
  }
  const float sc = 0.088388347648318447f;  // 1/sqrt(128)
  float s0 = d0 * sc, s1 = d1 * sc;
  float mx = fmaxf(s0, s1);
  float e0 = expf(s0 - mx), e1 = expf(s1 - mx);
  float r = 1.f / (e0 + e1);
  float a0 = e0 * r, a1 = e1 * r;
  ushort4 o;
  o.x = f2b(a0 * b2f(v0v.x) + a1 * b2f(v1v.x));
  o.y = f2b(a0 * b2f(v0v.y) + a1 * b2f(v1v.y));
  o.z = f2b(a0 * b2f(v0v.z) + a1 * b2f(v1v.z));
  o.w = f2b(a0 * b2f(v0v.w) + a1 * b2f(v1v.w));
  *(ushort4*)(O + bo) = o;
}

// ---------------- final: out[row] = dot(LN(X + Y)*g + b, Wc) + bc ----------------
__global__ __launch_bounds__(256)
void final_k(const u16* __restrict__ X, const u16* __restrict__ Y,
             const float* __restrict__ g, const float* __restrict__ bta,
             const float* __restrict__ Wc, const float* __restrict__ bc,
             float* __restrict__ out)
{
  const int row = blockIdx.x;
  const int tid = threadIdx.x;
  const size_t base = (size_t)row * 1024 + tid * 4;
  ushort4 xv = *(const ushort4*)(X + base);
  ushort4 yv = *(const ushort4*)(Y + base);
  float v0 = b2f(xv.x) + b2f(yv.x);
  float v1 = b2f(xv.y) + b2f(yv.y);
  float v2 = b2f(xv.z) + b2f(yv.z);
  float v3 = b2f(xv.w) + b2f(yv.w);
  float s  = v0 + v1 + v2 + v3;
  float ss = v0*v0 + v1*v1 + v2*v2 + v3*v3;
#pragma unroll
  for (int off = 32; off; off >>= 1) {
    s  += __shfl_down(s, off);
    ss += __shfl_down(ss, off);
  }
  __shared__ float red[8];
  __shared__ float red2[4];
  if ((tid & 63) == 0) { red[tid >> 6] = s; red[4 + (tid >> 6)] = ss; }
  __syncthreads();
  const float S  = red[0] + red[1] + red[2] + red[3];
  const float SS = red[4] + red[5] + red[6] + red[7];
  const float mu  = S * (1.f / 1024.f);
  const float inv = rsqrtf(SS * (1.f / 1024.f) - mu * mu + 1e-5f);
  const int n = tid * 4;
  float4 gv = *(const float4*)(g + n);
  float4 bv = *(const float4*)(bta + n);
  float4 wv = *(const float4*)(Wc + n);
  float dot = ((v0 - mu) * inv * gv.x + bv.x) * wv.x
            + ((v1 - mu) * inv * gv.y + bv.y) * wv.y
            + ((v2 - mu) * inv * gv.z + bv.z) * wv.z
            + ((v3 - mu) * inv * gv.w + bv.w) * wv.w;
#pragma unroll
  for (int off = 32; off; off >>= 1) dot += __shfl_down(dot, off);
  if ((tid & 63) == 0) red2[tid >> 6] = dot;
  __syncthreads();
  if (tid == 0) out[row] = red2[0] + red2[1] + red2[2] + red2[3] + bc[0];
}

// =====================================================================
extern "C" void kernel_launch(void* const* d_in, const int* in_sizes, int n_in,
                              void* d_out, int out_size, void* d_ws, size_t ws_size,
                              hipStream_t stream) {
  const float* spatial = (const float*)d_in[0];
  const float* freq    = (const float*)d_in[1];
  const float* Wps   = (const float*)d_in[2];
  const float* bps   = (const float*)d_in[3];
  const float* Wpf   = (const float*)d_in[4];
  const float* bpf   = (const float*)d_in[5];
  // d_in[8], d_in[9], d_in[11], d_in[12] (ca_Wq/ca_Wk/ca_bq/ca_bk) are dead: softmax over 1 key == 1
  const float* pos_s = (const float*)d_in[6];
  const float* pos_f = (const float*)d_in[7];
  const float* ca_Wv = (const float*)d_in[10];
  const float* ca_bv = (const float*)d_in[13];
  const float* ca_Wo = (const float*)d_in[14];
  const float* ca_bo = (const float*)d_in[15];
  const float* n1_g  = (const float*)d_in[16];
  const float* n1_b  = (const float*)d_in[17];
  const float* W1    = (const float*)d_in[18];
  const float* b1    = (const float*)d_in[19];
  const float* W2    = (const float*)d_in[20];
  const float* b2    = (const float*)d_in[21];
  const float* n2_g  = (const float*)d_in[22];
  const float* n2_b  = (const float*)d_in[23];
  const float* sWq   = (const float*)d_in[24];
  const float* sWk   = (const float*)d_in[25];
  const float* sWv   = (const float*)d_in[26];
  const float* sbq   = (const float*)d_in[27];
  const float* sbk   = (const float*)d_in[28];
  const float* sbv   = (const float*)d_in[29];
  const float* sWo   = (const float*)d_in[30];
  const float* sbo   = (const float*)d_in[31];
  const float* n3_g  = (const float*)d_in[32];
  const float* n3_b  = (const float*)d_in[33];
  const float* Wc    = (const float*)d_in[34];
  const float* bc    = (const float*)d_in[35];

  const int Bn = 16384;
  constexpr size_t SZ_BIG = (size_t)16384 * 2048 * 2;   // 64 MiB
  constexpr size_t SZ_ACT = (size_t)16384 * 1024 * 2;   // 32 MiB
  constexpr size_t OFF_S = 0;
  constexpr size_t OFF_A = OFF_S + SZ_BIG;
  constexpr size_t OFF_B = OFF_A + SZ_ACT;   // == 96 MiB
  constexpr size_t OFF_C = OFF_B + SZ_ACT;
  constexpr size_t OFF_D = OFF_C + SZ_ACT;
  constexpr size_t OFF_E = OFF_D + SZ_ACT;
  constexpr size_t OFF_F = OFF_E + SZ_ACT;
  constexpr size_t OFF_W = OFF_F + SZ_ACT;

  uint8_t* ws = (uint8_t*)d_ws;
  u16* S_b  = (u16*)(ws + OFF_S);   // spatial bf16 (later Gb; later qkv[0:96MB))
  u16* F_b  = (u16*)(ws + OFF_A);   // freq bf16
  u16* Qb   = (u16*)(ws + OFF_B);   // (later Hb)
  u16* KVb  = (u16*)(ws + OFF_C);   // live until kv1 GEMM; then Ob
  u16* Vb   = (u16*)(ws + OFF_D);   // (later X2b)
  u16* AOb  = (u16*)(ws + OFF_E);   // (later kv1[0:64MB))
  u16* X1b  = (u16*)(ws + OFF_F);

  u16* wWps = (u16*)(ws + OFF_W);
  u16* wWpf = wWps + (size_t)1024 * 2048;
  u16* wWv  = wWpf + (size_t)1024 * 1024;
  u16* wWo  = wWv  + (size_t)1024 * 1024;
  u16* wW1  = wWo  + (size_t)1024 * 1024;
  u16* wW2  = wW1  + (size_t)2048 * 1024;
  u16* wSq  = wW2  + (size_t)1024 * 2048;   // wSq|wSk|wSv contiguous -> batched N=3072 GEMM
  u16* wSk  = wSq  + (size_t)1024 * 1024;
  u16* wSv  = wSk  + (size_t)1024 * 1024;
  u16* wSo  = wSv  + (size_t)1024 * 1024;
  float* bQKV = (float*)(wSo + (size_t)1024 * 1024);  // 3072 f32: sbq|sbk|sbv
  float* bKV  = bQKV + 3072;                          // 2048 f32: sbk|sbv

  // aliases (phase-based reuse)
  u16* Gb  = (u16*)(ws + OFF_S);
  u16* Hb  = (u16*)(ws + OFF_B);
  u16* X2b = (u16*)(ws + OFF_D);
  u16* qkv = (u16*)(ws + OFF_S);             // [16384][3072] : q0|k0|v0
  u16* kv1 = (u16*)(ws + OFF_E);             // [16384][2048] : k1|v1
  u16* Ob  = (u16*)(ws + OFF_C);
  u16* POb = (u16*)(ws + OFF_S);             // qkv region free after attn2

  auto cvt = [&](const float* src, u16* dst, size_t n) {
    int n4 = (int)(n >> 2);
    cvt_kernel<<<dim3((n4 + 255) / 256), dim3(256), 0, stream>>>(src, dst, n4);
  };
  auto gemm = [&](const u16* A_, const u16* W_, const float* bias, const float* bias2,
                  u16* C_, int N, int K, bool gelu) {
    const int nTn = N >> 8;
    dim3 grid(64 * nTn);   // (16384/256) * (N/256); always % 8 == 0
    if (gelu) gemm256<1><<<grid, dim3(512), 0, stream>>>(A_, W_, bias, bias2, C_, N, K, nTn);
    else      gemm256<0><<<grid, dim3(512), 0, stream>>>(A_, W_, bias, bias2, C_, N, K, nTn);
  };

  // 0) convert inputs + weights to bf16; concat self-attn biases (d2d, capture-safe)
  cvt(spatial, S_b, (size_t)Bn * 2048);
  cvt(freq,    F_b, (size_t)Bn * 1024);
  cvt(Wps, wWps, (size_t)1024 * 2048);
  cvt(Wpf, wWpf, (size_t)1024 * 1024);
  cvt(ca_Wv, wWv, (size_t)1024 * 1024);
  cvt(ca_Wo, wWo, (size_t)1024 * 1024);
  cvt(W1, wW1, (size_t)2048 * 1024);
  cvt(W2, wW2, (size_t)1024 * 2048);
  cvt(sWq, wSq, (size_t)1024 * 1024);
  cvt(sWk, wSk, (size_t)1024 * 1024);
  cvt(sWv, wSv, (size_t)1024 * 1024);
  cvt(sWo, wSo, (size_t)1024 * 1024);
  hipMemcpyAsync(bQKV,        sbq, 1024 * sizeof(float), hipMemcpyDeviceToDevice, stream);
  hipMemcpyAsync(bQKV + 1024, sbk, 1024 * sizeof(float), hipMemcpyDeviceToDevice, stream);
  hipMemcpyAsync(bQKV + 2048, sbv, 1024 * sizeof(float), hipMemcpyDeviceToDevice, stream);
  hipMemcpyAsync(bKV,         sbk, 1024 * sizeof(float), hipMemcpyDeviceToDevice, stream);
  hipMemcpyAsync(bKV + 1024,  sbv, 1024 * sizeof(float), hipMemcpyDeviceToDevice, stream);

  // 1) Q = spatial @ Wps^T + bps + pos_s
  gemm(S_b, wWps, bps, pos_s, Qb, 1024, 2048, false);
  // 2) KV = freq @ Wpf^T + bpf + pos_f
  gemm(F_b, wWpf, bpf, pos_f, KVb, 1024, 1024, false);
  // 3) V = KV @ ca_Wv^T + ca_bv ; 4) AO = V @ ca_Wo^T + ca_bo  (cross-attn collapsed)
  gemm(KVb, wWv, ca_bv, nullptr, Vb, 1024, 1024, false);
  gemm(Vb, wWo, ca_bo, nullptr, AOb, 1024, 1024, false);
  // 5) X1 = LN(Q + AO)
  ln_res<<<dim3(Bn), dim3(256), 0, stream>>>(Qb, AOb, n1_g, n1_b, X1b);
  // 6) G = gelu(X1 @ W1^T + b1) ; 7) H = G @ W2^T + b2
  gemm(X1b, wW1, b1, nullptr, Gb, 2048, 1024, true);
  gemm(Gb, wW2, b2, nullptr, Hb, 1024, 2048, false);
  // 8) X2 = LN(X1 + H)
  ln_res<<<dim3(Bn), dim3(256), 0, stream>>>(X1b, Hb, n2_g, n2_b, X2b);
  // 9) [q0|k0|v0] = X2 @ [Wq|Wk|Wv]^T  (batched, N=3072)
  gemm(X2b, wSq, bQKV, nullptr, qkv, 3072, 1024, false);
  // 10) [k1|v1] = KV @ [Wk|Wv]^T  (batched, N=2048)
  gemm(KVb, wSk, bKV, nullptr, kv1, 2048, 1024, false);
  // 11) 2-key attention combine per head
  attn2<<<dim3(Bn), dim3(256), 0, stream>>>(qkv, qkv + 1024, qkv + 2048, 3072,
                                            kv1, kv1 + 1024, 2048, Ob);
  // 12) PO = O @ sa_Wo^T + sa_bo
  gemm(Ob, wSo, sbo, nullptr, POb, 1024, 1024, false);
  // 13) out = LN(X2 + PO; n3) . Wc + bc
  final_k<<<dim3(Bn), dim3(256), 0, stream>>>(X2b, POb, n3_g, n3_b, Wc, bc, (float*)d_out);
}